// Round 1
// baseline (245.731 us; speedup 1.0000x reference)
//
#include <hip/hip_runtime.h>

// GraphProjection: out[N,963] = concat(verts[N,3], proj(f0)[N,64], proj(f1)[N,128],
//                                      proj(f2)[N,256], proj(f3)[N,512])
// Degenerate "bilinear": weights collapse to w11 = (x2-x1)*(y2-y1) in {0,1};
// every feature element is a masked gather of feat[c, floor(x), floor(y)].

static constexpr int NV      = 50000;
static constexpr int TOTAL   = 963 * NV;          // 48,150,000
static constexpr int B_VERTS = 3 * NV;            // 150,000
static constexpr int B_F0    = B_VERTS + 64 * NV; // 3,350,000
static constexpr int B_F1    = B_F0 + 128 * NV;   // 9,750,000
static constexpr int B_F2    = B_F1 + 256 * NV;   // 22,550,000

// transposed feature sizes (floats): [S*S, C]
static constexpr int T0 = 56 * 56 * 64;   // 200,704
static constexpr int T1 = 28 * 28 * 128;  // 100,352
static constexpr int T2 = 14 * 14 * 256;  // 50,176
static constexpr int T3 = 7 * 7 * 512;    // 25,088
static constexpr int TSUM = T0 + T1 + T2 + T3; // 376,320

__device__ __forceinline__ void proj_hw(const float* __restrict__ verts, int n,
                                        float& h, float& w) {
  float v0 = verts[3 * n + 0];
  float v1 = verts[3 * n + 1];
  float v2 = verts[3 * n + 2];
  // match numpy fp32 exactly: no FMA contraction, IEEE rn division
  h = __fadd_rn(__fmul_rn(248.0f, __fdiv_rn(v1, v2)), 111.5f);
  w = __fadd_rn(__fmul_rn(248.0f, __fdiv_rn(v0, -v2)), 111.5f);
  h = fminf(fmaxf(h, 0.0f), 223.0f);
  w = fminf(fmaxf(w, 0.0f), 223.0f);
}

__device__ __forceinline__ int level_off(float h, float w, float scale, int S) {
  float x = h * scale;  // scale = S/224 is an exact power of two
  float y = w * scale;
  int x1 = (int)floorf(x);
  int x2 = min((int)ceilf(x), S - 1);
  int y1 = (int)floorf(y);
  int y2 = min((int)ceilf(y), S - 1);
  return (x2 > x1 && y2 > y1) ? (x1 * S + y1) : -1;
}

__global__ __launch_bounds__(256) void prep_params_k(const float* __restrict__ verts,
                                                     int* __restrict__ params) {
  int n = blockIdx.x * 256 + threadIdx.x;
  if (n >= NV) return;
  float h, w;
  proj_hw(verts, n, h, w);
  params[4 * n + 0] = level_off(h, w, 0.25f,    56);
  params[4 * n + 1] = level_off(h, w, 0.125f,   28);
  params[4 * n + 2] = level_off(h, w, 0.0625f,  14);
  params[4 * n + 3] = level_off(h, w, 0.03125f, 7);
}

// [C,S,S] -> [S*S, C] so per-wave channel gathers are contiguous
__global__ __launch_bounds__(256) void transpose_k(
    const float* __restrict__ f0, const float* __restrict__ f1,
    const float* __restrict__ f2, const float* __restrict__ f3,
    float* __restrict__ t0, float* __restrict__ t1,
    float* __restrict__ t2, float* __restrict__ t3) {
  int i = blockIdx.x * 256 + threadIdx.x;
  if (i < T0) { int off = i >> 6, c = i & 63;  t0[i] = f0[c * 3136 + off]; return; }
  i -= T0;
  if (i < T1) { int off = i >> 7, c = i & 127; t1[i] = f1[c * 784 + off];  return; }
  i -= T1;
  if (i < T2) { int off = i >> 8, c = i & 255; t2[i] = f2[c * 196 + off];  return; }
  i -= T2;
  if (i < T3) { int off = i >> 9, c = i & 511; t3[i] = f3[c * 49 + off];   return; }
}

// MODE 0: transposed feats + params; MODE 1: original feats + params;
// MODE 2: original feats, params computed inline (tiny-ws fallback)
template <int MODE>
__device__ __forceinline__ int get_off(const int* __restrict__ params,
                                       const float* __restrict__ verts,
                                       int n, int k, float scale, int S) {
  if (MODE < 2) return params[4 * n + k];
  float h, w;
  proj_hw(verts, n, h, w);
  return level_off(h, w, scale, S);
}

template <int MODE>
__global__ __launch_bounds__(256) void gp_main_k(
    const float* __restrict__ verts,
    const float* __restrict__ f0, const float* __restrict__ f1,
    const float* __restrict__ f2, const float* __restrict__ f3,
    const int* __restrict__ params, float* __restrict__ out) {
  int j = blockIdx.x * 256 + threadIdx.x;
  if (j >= TOTAL) return;

  if (j < B_VERTS) {  // verts passthrough: out[n*963 + col] = verts[j]
    int n = j / 3;
    int col = j - 3 * n;
    out[n * 963 + col] = verts[j];
    return;
  }

  int n, outcol;
  float val = 0.0f;
  if (j < B_F0) {
    int t = j - B_VERTS; n = t >> 6; int c = t & 63;
    int off = get_off<MODE>(params, verts, n, 0, 0.25f, 56);
    if (off >= 0) val = (MODE == 0) ? f0[(off << 6) + c] : f0[c * 3136 + off];
    outcol = 3 + c;
  } else if (j < B_F1) {
    int t = j - B_F0; n = t >> 7; int c = t & 127;
    int off = get_off<MODE>(params, verts, n, 1, 0.125f, 28);
    if (off >= 0) val = (MODE == 0) ? f1[(off << 7) + c] : f1[c * 784 + off];
    outcol = 67 + c;
  } else if (j < B_F2) {
    int t = j - B_F1; n = t >> 8; int c = t & 255;
    int off = get_off<MODE>(params, verts, n, 2, 0.0625f, 14);
    if (off >= 0) val = (MODE == 0) ? f2[(off << 8) + c] : f2[c * 196 + off];
    outcol = 195 + c;
  } else {
    int t = j - B_F2; n = t >> 9; int c = t & 511;
    int off = get_off<MODE>(params, verts, n, 3, 0.03125f, 7);
    if (off >= 0) val = (MODE == 0) ? f3[(off << 9) + c] : f3[c * 49 + off];
    outcol = 451 + c;
  }
  out[n * 963 + outcol] = val;
}

extern "C" void kernel_launch(void* const* d_in, const int* in_sizes, int n_in,
                              void* d_out, int out_size, void* d_ws, size_t ws_size,
                              hipStream_t stream) {
  const float* f0    = (const float*)d_in[0];
  const float* f1    = (const float*)d_in[1];
  const float* f2    = (const float*)d_in[2];
  const float* f3    = (const float*)d_in[3];
  const float* verts = (const float*)d_in[4];
  float* out = (float*)d_out;

  const size_t PARAM_BYTES = (size_t)NV * 4 * sizeof(int);           // 800,000 (16B-aligned)
  const size_t FULL_BYTES  = PARAM_BYTES + (size_t)TSUM * sizeof(float); // 2,305,280

  const int mainBlocks = (TOTAL + 255) / 256;

  if (ws_size >= FULL_BYTES) {
    int*   params = (int*)d_ws;
    float* t0 = (float*)((char*)d_ws + PARAM_BYTES);
    float* t1 = t0 + T0;
    float* t2 = t1 + T1;
    float* t3 = t2 + T2;
    prep_params_k<<<(NV + 255) / 256, 256, 0, stream>>>(verts, params);
    transpose_k<<<(TSUM + 255) / 256, 256, 0, stream>>>(f0, f1, f2, f3, t0, t1, t2, t3);
    gp_main_k<0><<<mainBlocks, 256, 0, stream>>>(verts, t0, t1, t2, t3, params, out);
  } else if (ws_size >= PARAM_BYTES) {
    int* params = (int*)d_ws;
    prep_params_k<<<(NV + 255) / 256, 256, 0, stream>>>(verts, params);
    gp_main_k<1><<<mainBlocks, 256, 0, stream>>>(verts, f0, f1, f2, f3, params, out);
  } else {
    gp_main_k<2><<<mainBlocks, 256, 0, stream>>>(verts, f0, f1, f2, f3, nullptr, out);
  }
}